// Round 7
// baseline (206.156 us; speedup 1.0000x reference)
//
#include <hip/hip_runtime.h>

#define H 512
#define WID 1024
#define HW (H*WID)
#define B 4
#define K 8
#define NB 1024
#define NBLK1 128                          // kA blocks per image
#define G3 64                              // kB blocks per image

// ws word (4-byte) layout
#define OFF_LOSS  0
#define OFF_CTRA  8                        // kA done-counter (u32)
#define OFF_CTRC  9                        // kC done-counter (u32)
#define OFF_FIN   16                       // B*K*8 floats: a,bx,by,d0,cnt,pad*3
#define OFF_SPART 512                      // B*K*NBLK1*5 floats (kA partials)
#define OFF_PART  (OFF_SPART + B*K*NBLK1*5)    // B*G3*K*NB packed u32 (pos<<16|cnt)

static __device__ __forceinline__ float frcp(float x){
#if __has_builtin(__builtin_amdgcn_rcpf)
  return __builtin_amdgcn_rcpf(x);
#else
  return 1.0f / x;
#endif
}
static __device__ __forceinline__ float fexp2(float x){
#if __has_builtin(__builtin_amdgcn_exp2f)
  return __builtin_amdgcn_exp2f(x);
#else
  return exp2f(x);
#endif
}
static __device__ __forceinline__ float ftanh(float x){
  return 1.0f - 2.0f * frcp(__expf(2.0f*x) + 1.0f);
}
static __device__ __forceinline__ float fsigmoid(float x){
  return frcp(1.0f + __expf(-x));
}

// ======== Kernel A: per-(b,k) stats + last-block finalize (old k1+k2) ========
__global__ __launch_bounds__(512) void kA_stats(const float* __restrict__ pred,
                                                const int* __restrict__ inst,
                                                float* __restrict__ ws,
                                                unsigned int* __restrict__ ctr) {
  const int b = blockIdx.y;
  __shared__ int4   ti[1024];
  __shared__ float4 ts[1024];
  __shared__ float  part5[K][5];
  const float4* sig4 = (const float4*)(pred + (size_t)(8*b + 5) * HW);  // ch2 t=1
  const int4*   ins4 = (const int4*)(inst + (size_t)(2*b + 1) * HW);
  const int base4 = blockIdx.x * 1024;     // 1024 int4-groups (4096 px) per block
  #pragma unroll
  for (int i = 0; i < 2; i++) {
    const int q = threadIdx.x + i*512;
    ti[q] = ins4[base4 + q];
    ts[q] = sig4[base4 + q];
  }
  __syncthreads();
  const int wv = threadIdx.x >> 6, lane = threadIdx.x & 63;
  const int kk = wv + 1;
  float cnt=0.f, sx=0.f, sy=0.f, ss=0.f, ss2=0.f;
  #pragma unroll
  for (int j = 0; j < 16; j++) {
    const int q = lane + 64*j;
    const int4   iv = ti[q];
    const float4 sv = ts[q];
    const int p = (base4 + q) * 4;
    const float xm0 = (float)(p & (WID-1)) * (2.0f/2047.0f);
    const float ym  = (float)(p >> 10)     * (1.0f/1023.0f);
    const float m0 = (iv.x==kk)?1.f:0.f, m1=(iv.y==kk)?1.f:0.f,
                m2 = (iv.z==kk)?1.f:0.f, m3=(iv.w==kk)?1.f:0.f;
    const float msum = (m0+m1)+(m2+m3);
    cnt += msum;
    sx  += msum*xm0 + (m1 + 2.0f*m2 + 3.0f*m3)*(2.0f/2047.0f);
    sy  += msum*ym;
    ss  += m0*sv.x + m1*sv.y + m2*sv.z + m3*sv.w;
    ss2 += m0*sv.x*sv.x + m1*sv.y*sv.y + m2*sv.z*sv.z + m3*sv.w*sv.w;
  }
  #pragma unroll
  for (int o=1;o<64;o<<=1){
    cnt+=__shfl_xor(cnt,o,64);
    sx +=__shfl_xor(sx, o,64);
    sy +=__shfl_xor(sy, o,64);
    ss +=__shfl_xor(ss, o,64);
    ss2+=__shfl_xor(ss2,o,64);
  }
  if (lane == 0) {
    part5[wv][0]=cnt; part5[wv][1]=sx; part5[wv][2]=sy; part5[wv][3]=ss; part5[wv][4]=ss2;
  }
  __syncthreads();
  if (threadIdx.x < K*5) {
    const int w = threadIdx.x / 5, c = threadIdx.x % 5;
    ws[OFF_SPART + ((size_t)(b*K + w)*NBLK1 + blockIdx.x)*5 + c] = part5[w][c];
  }
  // ---- last-block-takes-all finalize ----
  __threadfence();
  __shared__ int lastB;
  if (threadIdx.x == 0)
    lastB = (atomicAdd(ctr, 1u) == (unsigned)(NBLK1*B - 1)) ? 1 : 0;
  __syncthreads();
  if (!lastB) return;
  __threadfence();                          // acquire: see other blocks' spart stores
  const int t = threadIdx.x;
  const int bk = t >> 4, s = t & 15;        // 32 bk x 16 slices
  float a0=0.f,a1=0.f,a2=0.f,a3=0.f,a4=0.f;
  #pragma unroll
  for (int j = 0; j < NBLK1/16; j++) {
    const float* p = ws + OFF_SPART + ((size_t)bk*NBLK1 + (s + 16*j))*5;
    a0+=p[0]; a1+=p[1]; a2+=p[2]; a3+=p[3]; a4+=p[4];
  }
  #pragma unroll
  for (int o=1;o<16;o<<=1){
    a0+=__shfl_xor(a0,o,64); a1+=__shfl_xor(a1,o,64); a2+=__shfl_xor(a2,o,64);
    a3+=__shfl_xor(a3,o,64); a4+=__shfl_xor(a4,o,64);
  }
  __shared__ float vloc[32];
  if (s == 0) {
    const float cntT=a0, sx2=a1, sy2=a2, ss1=a3, ss21=a4;
    const float present = (cntT > 0.0f) ? 1.0f : 0.0f;
    const float safe = fmaxf(cntT, 1.0f);
    const float cx = sx2/safe, cy = sy2/safe, sm = ss1/safe;
    const float var = (ss21 - 2.0f*sm*ss1 + sm*sm*cntT)/safe;   // N_SIGMA=1
    const float sexp = expf(10.0f * sm);
    const float L2E = 1.4426950408889634f;
    float* fin = ws + OFF_FIN + bk*8;
    fin[0] = -sexp*L2E;                       // a
    fin[1] =  2.0f*sexp*cx*L2E;               // bx
    fin[2] =  2.0f*sexp*cy*L2E;               // by
    fin[3] = -sexp*(cx*cx + cy*cy)*L2E + 10.0f;  // d0 (+10 folds 1024 bucket scale)
    fin[4] = cntT;
    vloc[bk] = present * 10.0f * var * (1.0f/3.0f);   // W_VAR=10, /(B-1)
  }
  __syncthreads();
  if (t == 0) {
    float v = 0.f;
    #pragma unroll
    for (int i = 0; i < 32; i++) v += vloc[i];
    ws[OFF_LOSS] = v;                         // first/only writer at this point
  }
}

// ======== Kernel B: main pass — 3-FMA log2 bucketing, plain-store flush ========
__global__ __launch_bounds__(256) void kB_main(const float* __restrict__ pred,
                                               const int* __restrict__ inst,
                                               float* __restrict__ ws,
                                               unsigned int* __restrict__ part) {
  const int b = blockIdx.y, g = blockIdx.x;
  __shared__ unsigned int hist[K*NB];           // pos<<16 | cnt, 32 KiB
  for (int i = threadIdx.x; i < K*NB; i += 256) hist[i] = 0;
  float4 fr[K];
  #pragma unroll
  for (int k=0;k<K;k++){
    const float* fin = ws + OFF_FIN + (b*K + k)*8;
    fr[k] = make_float4(fin[0], fin[1], fin[2], fin[3]);  // {a,bx,by,d0}
  }
  __syncthreads();
  const float4* p0 = (const float4*)(pred + (size_t)(8*b+1)*HW);
  const float4* p1 = (const float4*)(pred + (size_t)(8*b+3)*HW);
  const float4* p3 = (const float4*)(pred + (size_t)(8*b+7)*HW);
  const int4*   in4 = (const int4*)(inst + (size_t)(2*b+1)*HW);
  float sAcc = 0.0f;
  constexpr int CH4 = HW / (G3*4);              // 2048 int4-groups per block
  const int base4 = g * CH4;
  #pragma unroll
  for (int q0 = 0; q0 < CH4; q0 += 256) {
    const int idx = base4 + q0 + threadIdx.x;
    const int4   iv = in4[idx];
    const float4 f0 = p0[idx];
    const float4 f1 = p1[idx];
    const float4 f3 = p3[idx];
    const int p = idx * 4;
    const float xm0 = (float)(p & (WID-1)) * (2.0f/2047.0f);
    const float ym  = (float)(p >> 10)     * (1.0f/1023.0f);
    const int   ivv[4] = {iv.x, iv.y, iv.z, iv.w};
    const float a0v[4] = {f0.x, f0.y, f0.z, f0.w};
    const float a1v[4] = {f1.x, f1.y, f1.z, f1.w};
    const float a3v[4] = {f3.x, f3.y, f3.z, f3.w};
    #pragma unroll
    for (int e4 = 0; e4 < 4; e4++) {
      const int ivp = ivv[e4];
      const float px = ftanh(a0v[e4]) + xm0 + (float)e4*(2.0f/2047.0f);
      const float py = ftanh(a1v[e4]) + ym;
      const float sd = fsigmoid(a3v[e4]);
      const float t2 = px*px + py*py;
      float down = 0.0f;
      #pragma unroll
      for (int j=0;j<K;j++){
        const float u = fmaf(fr[j].x, t2, fmaf(fr[j].y, px, fmaf(fr[j].z, py, fr[j].w)));
        const float v = fexp2(u);                 // 1024*dist in [0,1024]
        int vi = (int)v; vi = (vi > NB-1) ? NB-1 : vi;
        const bool own = (ivp == j+1);
        const int bu = own ? (NB-1 - vi) : vi;
        if (own) down = v;
        atomicAdd(&hist[j*NB + bu], own ? 0x10001u : 1u);
      }
      const float d  = (ivp == 0) ? 0.0f : down * (1.0f/1024.0f);
      const float df = sd - d;
      sAcc += df*df;                              // bg: sd^2; fg: (sd-dist)^2
    }
  }
  __syncthreads();
  unsigned int* dst = part + ((size_t)b*G3 + g)*(K*NB);
  for (int i = threadIdx.x; i < K*NB; i += 256) dst[i] = hist[i];
  #pragma unroll
  for (int o=1;o<64;o<<=1) sAcc += __shfl_xor(sAcc, o, 64);
  __shared__ float wsum[4];
  if ((threadIdx.x & 63) == 0) wsum[threadIdx.x>>6] = sAcc;
  __syncthreads();
  if (threadIdx.x == 0) {
    const float tot = wsum[0]+wsum[1]+wsum[2]+wsum[3];
    atomicAdd(ws + OFF_LOSS, tot * (1.0f/((float)HW * 3.0f)));  // W_SEED /npix /(B-1)
  }
}

// ======== Kernel C: G-way reduce + Lovász + output (old k4a+k4b+k5) ========
__global__ __launch_bounds__(512) void kC_lovasz(const unsigned int* __restrict__ part,
                                                 float* __restrict__ ws,
                                                 float* __restrict__ out,
                                                 unsigned int* __restrict__ ctr) {
  const int bk = blockIdx.x;                    // b*K + k
  const int b = bk >> 3, k = bk & 7;
  const int t = threadIdx.x, lane = t & 63, wv = t >> 6;
  // thread t owns descending positions 2t, 2t+1 -> buckets bu0 = NB-1-2t, bu1 = bu0-1
  const int bu0 = NB-1 - 2*t, bu1 = bu0 - 1;
  const unsigned int* base = part + (size_t)b*G3*K*NB + (size_t)k*NB;
  unsigned int c0=0,pz0=0,c1=0,pz1=0;
  #pragma unroll 4
  for (int g = 0; g < G3; g++) {
    const unsigned int v0 = base[(size_t)g*K*NB + bu0];
    const unsigned int v1 = base[(size_t)g*K*NB + bu1];
    c0 += v0 & 0xFFFFu;  pz0 += v0 >> 16;
    c1 += v1 & 0xFFFFu;  pz1 += v1 >> 16;
  }
  const float cntF = ws[OFF_FIN + bk*8 + 4];
  const int lc = (int)(c0 + c1), lp = (int)(pz0 + pz1);
  int ic = lc, ip = lp;
  #pragma unroll
  for (int o=1;o<64;o<<=1){
    const int vc = __shfl_up(ic, o, 64);
    const int vp = __shfl_up(ip, o, 64);
    if (lane >= o) { ic += vc; ip += vp; }
  }
  __shared__ int wtc[8], wtp[8];
  if (lane == 63) { wtc[wv] = ic; wtp[wv] = ip; }
  __syncthreads();
  int offc = 0, offp = 0;
  for (int w = 0; w < wv; w++) { offc += wtc[w]; offp += wtp[w]; }
  int irun = offc + ic - lc;                    // exclusive prefixes
  int crun = offp + ip - lp;
  double acc = 0.0;
  if (cntF > 0.0f) {
    const double Pd = (double)cntF;
    if (c0) {
      const double jac0 = (irun==0) ? 0.0 : 1.0 - (Pd - crun)/(Pd + irun - crun);
      irun += (int)c0; crun += (int)pz0;
      const double jac1 = 1.0 - (Pd - crun)/(Pd + irun - crun);
      acc += ((bu0 + 0.5) * (2.0/NB)) * (jac1 - jac0);
    } else irun += (int)c0;
    if (c1) {
      const double jac0 = (irun==0) ? 0.0 : 1.0 - (Pd - crun)/(Pd + irun - crun);
      irun += (int)c1; crun += (int)pz1;
      const double jac1 = 1.0 - (Pd - crun)/(Pd + irun - crun);
      acc += ((bu1 + 0.5) * (2.0/NB)) * (jac1 - jac0);
    }
  }
  #pragma unroll
  for (int o=1;o<64;o<<=1) acc += __shfl_xor(acc, o, 64);
  __shared__ double racc[8];
  if (lane == 0) racc[wv] = acc;
  __syncthreads();
  if (t == 0) {
    double tot = 0.0;
    #pragma unroll
    for (int i = 0; i < 8; i++) tot += racc[i];
    atomicAdd(ws + OFF_LOSS, (float)(tot * (1.0/3.0)));   // W_INST=1, /(B-1)
  }
  // ---- last block writes the output ----
  __threadfence();
  __shared__ int lastB;
  if (t == 0) lastB = (atomicAdd(ctr, 1u) == (unsigned)(B*K - 1)) ? 1 : 0;
  __syncthreads();
  if (lastB && t == 0) {
    __threadfence();
    out[0] = atomicAdd(ws + OFF_LOSS, 0.0f);  // atomic read-modify-write fetch
  }
}

extern "C" void kernel_launch(void* const* d_in, const int* in_sizes, int n_in,
                              void* d_out, int out_size, void* d_ws, size_t ws_size,
                              hipStream_t stream) {
  const float* pred = (const float*)d_in[0];
  const int*   inst = (const int*)d_in[1];
  float* ws  = (float*)d_ws;
  float* out = (float*)d_out;
  unsigned int* ctrA = ((unsigned int*)d_ws) + OFF_CTRA;
  unsigned int* ctrC = ((unsigned int*)d_ws) + OFF_CTRC;
  unsigned int* part = ((unsigned int*)d_ws) + OFF_PART;
  hipMemsetAsync(d_ws, 0, 2048, stream);     // zero LOSS + counters + FIN
  kA_stats<<<dim3(NBLK1,B), 512, 0, stream>>>(pred, inst, ws, ctrA);
  kB_main <<<dim3(G3,B),   256, 0, stream>>>(pred, inst, ws, part);
  kC_lovasz<<<B*K,         512, 0, stream>>>(part, ws, out, ctrC);
}